// Round 1
// baseline (179.420 us; speedup 1.0000x reference)
//
#include <hip/hip_runtime.h>
#include <hip/hip_bf16.h>

// ---------------------------------------------------------------------------
// GlobalIntrinsicLinear: Fastfood update + GEMM
//   LL = 1<<20, DD = 1024*768, OUT=1024, IN=768, M = 8*2048 = 16384
// Inputs: x(8,2048,768) f32, theta(2048) f32, W_0(1024,768) f32, b(1024) f32,
//         BB(LL) f32, GG(LL) f32, Pi(LL) int32 (harness narrows int64)
// Output: (8,2048,1024) f32
//
// R8: (1) killed the x->bf16 cast pass: k7 now reads x f32 directly and
//     converts to bf16 during A staging (reg-stage + v_cvt_pk_bf16_f32 +
//     linear ds_write, same XOR-swizzled layout => inner loop unchanged).
//     Saves 75 MB of HBM traffic and k3's whole streaming tail.
//     (2) k4 split 128 blocks x 8 cols -> 256 blocks x 4 cols (2x parallelism,
//     half the serial butterfly work per block).
// ---------------------------------------------------------------------------

#define LL (1 << 20)
#define DD (1024 * 768)
#define OUTF 1024
#define INF 768
#define MROWS 16384

typedef __attribute__((ext_vector_type(8))) short s16x8;
typedef __attribute__((ext_vector_type(4))) float f32x4;
typedef __attribute__((ext_vector_type(16))) float f32x16;

__device__ __forceinline__ unsigned short f2bf(float f) {
    union { float f; unsigned u; } v; v.f = f;
    unsigned r = v.u + 0x7FFF + ((v.u >> 16) & 1);   // RNE
    return (unsigned short)(r >> 16);
}

// packed f32->bf16 RNE (same rounding as f2bf); no builtin on gfx950 (m240)
__device__ __forceinline__ unsigned cvt_pk_bf16(float lo, float hi) {
    unsigned r;
    asm("v_cvt_pk_bf16_f32 %0, %1, %2" : "=v"(r) : "v"(lo), "v"(hi));
    return r;
}

// ---------------------------------------------------------------------------
// K3: fused {FWHT-1024 of the two nonzero rows of BB*theta_pad} + gather +
// FWHT-1024 along low-10 bits + sum(GG^2) block partials.
// One hi-row per block (1024 blocks).
// Math: FWHT_{2^20} of a vector nonzero only at q<2048 collapses to
//   v1[p] = r0[p&1023] + (-1)^{bit10(p)} * r1[p&1023],  r0/r1 = FWHT_1024 rows.
// ---------------------------------------------------------------------------
__global__ void k3_gather_fwht_lo(const int* __restrict__ Pi, const float* __restrict__ GG,
                                  const float* __restrict__ BB, const float* __restrict__ theta,
                                  float* __restrict__ T, float* __restrict__ partial) {
    __shared__ float s[1024];
    __shared__ float r01s[2048];
    __shared__ float ws4[4];
    const int tid = threadIdx.x;
    const int row = blockIdx.x;
    // gather operands early (latency hidden behind r01 butterflies)
    const int4   pv = ((const int4*)Pi)[row * 256 + tid];
    const float4 gv = ((const float4*)GG)[row * 256 + tid];
    for (int j = tid; j < 2048; j += 256) r01s[j] = BB[j] * theta[j];
    for (int h = 1; h < 1024; h <<= 1) {
        __syncthreads();
        for (int w = tid; w < 1024; w += 256) {
            int rr = w >> 9;
            int b  = w & 511;
            int bh = b & (h - 1);
            int i  = ((b - bh) << 1) + bh + rr * 1024;
            float a = r01s[i], c = r01s[i + h];
            r01s[i] = a + c; r01s[i + h] = a - c;
        }
    }
    // sum(GG^2) partial for this block (no atomics)
    float g2 = gv.x * gv.x + gv.y * gv.y + gv.z * gv.z + gv.w * gv.w;
    #pragma unroll
    for (int o = 32; o > 0; o >>= 1) g2 += __shfl_down(g2, o, 64);
    if ((tid & 63) == 0) ws4[tid >> 6] = g2;
    __syncthreads();
    {
        int p; float g, v;
        p = pv.x; g = gv.x;
        v = (r01s[p & 1023] + (((p >> 10) & 1) ? -1.0f : 1.0f) * r01s[1024 + (p & 1023)]) * g;
        s[tid * 4 + 0] = v;
        p = pv.y; g = gv.y;
        v = (r01s[p & 1023] + (((p >> 10) & 1) ? -1.0f : 1.0f) * r01s[1024 + (p & 1023)]) * g;
        s[tid * 4 + 1] = v;
        p = pv.z; g = gv.z;
        v = (r01s[p & 1023] + (((p >> 10) & 1) ? -1.0f : 1.0f) * r01s[1024 + (p & 1023)]) * g;
        s[tid * 4 + 2] = v;
        p = pv.w; g = gv.w;
        v = (r01s[p & 1023] + (((p >> 10) & 1) ? -1.0f : 1.0f) * r01s[1024 + (p & 1023)]) * g;
        s[tid * 4 + 3] = v;
    }
    for (int h = 1; h < 1024; h <<= 1) {
        __syncthreads();
        for (int w = tid; w < 512; w += 256) {
            int bh = w & (h - 1);
            int i  = ((w - bh) << 1) + bh;
            float a = s[i], c = s[i + h];
            s[i] = a + c; s[i + h] = a - c;
        }
    }
    __syncthreads();
    float4 v;
    v.x = s[tid * 4 + 0]; v.y = s[tid * 4 + 1]; v.z = s[tid * 4 + 2]; v.w = s[tid * 4 + 3];
    ((float4*)T)[row * 256 + tid] = v;
    if (tid == 0) partial[row] = ws4[0] + ws4[1] + ws4[2] + ws4[3];
}

// ---------------------------------------------------------------------------
// K4: FWHT-1024 along the high-10 bits + W_eff epilogue.
// 256 blocks x 4 lo-columns each; LDS tile [4][1025] (pad -> conflict-free).
// Every block redundantly reduces the 1024 GG^2 partials (4 KB; no global S).
// Epilogue: WB[d] = bf16(W0[d] + v[d]*rsqrt(S*DD)) for d = hi*1024+lo < DD.
// ---------------------------------------------------------------------------
__global__ void k4_fwht_hi(const float* __restrict__ T, const float* __restrict__ partial,
                           const float* __restrict__ W0, ushort* __restrict__ WB) {
    __shared__ float s[4 * 1025];
    __shared__ float rw[5];
    const int tid = threadIdx.x;
    // per-block S reduction (partials from k3)
    float p = partial[tid] + partial[tid + 256] + partial[tid + 512] + partial[tid + 768];
    #pragma unroll
    for (int o = 32; o > 0; o >>= 1) p += __shfl_down(p, o, 64);
    if ((tid & 63) == 0) rw[tid >> 6] = p;

    const int lo0 = blockIdx.x * 4;            // 256 blocks x 4 columns
    const float4* T4 = (const float4*)T;
    #pragma unroll
    for (int hb = 0; hb < 4; hb++) {
        int hi = hb * 256 + tid;
        float4 v = T4[hi * 256 + (lo0 >> 2)];  // one float4 = this block's 4 cols
        s[0 * 1025 + hi] = v.x;
        s[1 * 1025 + hi] = v.y;
        s[2 * 1025 + hi] = v.z;
        s[3 * 1025 + hi] = v.w;
    }
    __syncthreads();
    if (tid == 0) rw[4] = rw[0] + rw[1] + rw[2] + rw[3];
    for (int h = 1; h < 1024; h <<= 1) {
        for (int w = tid; w < 4 * 512; w += 256) {
            int col = w >> 9;
            int b   = w & 511;
            int bh  = b & (h - 1);
            int i   = ((b - bh) << 1) + bh;
            float* pp = s + col * 1025;
            float a = pp[i], c = pp[i + h];
            pp[i] = a + c; pp[i + h] = a - c;
        }
        __syncthreads();
    }
    const float scale = rsqrtf(rw[4] * (float)DD);
    // epilogue: only hi < 768 maps into W (d = hi*1024 + lo < DD)
    #pragma unroll
    for (int hb = 0; hb < 3; hb++) {
        int hi = hb * 256 + tid;               // < 768 exactly
        int d  = hi * 1024 + lo0;              // 4-aligned
        float4 w = *(const float4*)&W0[d];
        ushort4 o;
        o.x = f2bf(w.x + s[0 * 1025 + hi] * scale);
        o.y = f2bf(w.y + s[1 * 1025 + hi] * scale);
        o.z = f2bf(w.z + s[2 * 1025 + hi] * scale);
        o.w = f2bf(w.w + s[3 * 1025 + hi] * scale);
        *(ushort4*)&WB[d] = o;
    }
}

// ---------------------------------------------------------------------------
// K7: GEMM  C[m][n] = sum_k A[m][k]*B[n][k] + bias[n]
// A: MROWS x 768 f32 (x, converted to bf16 in-staging), B: 1024 x 768 bf16.
// 128x128 tile, BK=64, 4 waves (2x2), each wave 2x2 MFMA 32x32x16 tiles
// x4 k-steps (K=16 each). 16 ds_read_b128 + 16 MFMA per K-iter.
// A staging: global f32 -> regs -> v_cvt_pk_bf16_f32 -> linear ds_write_b128
// with pre-swizzled SOURCE address (rule #21: linear dest + inv-swz source +
// swz on read). B staging: global_load_lds (unchanged).
// XOR-swizzled LDS: 16B slot s <-> row = s>>3, kc = (s&7) ^ (row&7).
// A-frag: m = lane&31, k = (lane>>5)*8 + j  (symmetric ext of 16x16x32).
// C/D: col = lane&31, row = (reg&3) + 8*(reg>>2) + 4*(lane>>5)  [m74/m101].
// ---------------------------------------------------------------------------
#define BM 128
#define BN 128
#define BK 64

__global__ __launch_bounds__(256)
void k7_gemm(const float* __restrict__ A, const ushort* __restrict__ B,
             const float* __restrict__ bias, float* __restrict__ C) {
    __shared__ ushort As[BM * BK];   // 16 KB (bf16 after in-staging cvt)
    __shared__ ushort Bs[BN * BK];   // 16 KB
    const int tid  = threadIdx.x;
    const int lane = tid & 63;
    const int wave = tid >> 6;
    const int m0 = blockIdx.x * BM;
    const int n0 = blockIdx.y * BN;
    const int wm = (wave & 1) * 64;
    const int wn = (wave >> 1) * 64;

    const int fr_row = lane & 31;     // row within 32-tile
    const int fr_kh  = lane >> 5;     // k-half 0..1 (8 k each)

    f32x16 acc[2][2];
    #pragma unroll
    for (int i = 0; i < 2; i++)
        #pragma unroll
        for (int j = 0; j < 2; j++) acc[i][j] = (f32x16)(0.0f);

    // per-thread A staging geometry (constant across kt): slot s = j*256+tid
    int arow[4], akc[4];
    #pragma unroll
    for (int j = 0; j < 4; j++) {
        const int s = j * 256 + tid;
        arow[j] = s >> 3;
        akc[j]  = (s & 7) ^ (arow[j] & 7);
    }

    // prologue: load first A tile (f32) into regs
    f32x4 ar[8];
    #pragma unroll
    for (int j = 0; j < 4; j++) {
        const float* ga = A + (size_t)(m0 + arow[j]) * INF + akc[j] * 8;
        ar[2 * j]     = *(const f32x4*)ga;
        ar[2 * j + 1] = *(const f32x4*)(ga + 4);
    }

    for (int kt = 0; kt < INF; kt += BK) {
        // --- B tile: 1024 slots x 16B, XOR-swizzled source, linear LDS dest ---
        #pragma unroll
        for (int i = 0; i < 4; i++) {
            const int s   = i * 256 + tid;       // LDS slot (16B units)
            const int row = s >> 3;
            const int kc  = (s & 7) ^ (row & 7);
            const ushort* gb = B + (size_t)(n0 + row) * INF + kt + kc * 8;
            __builtin_amdgcn_global_load_lds(
                (const __attribute__((address_space(1))) void*)gb,
                (__attribute__((address_space(3))) void*)&Bs[i * 2048 + wave * 512], 16, 0, 0);
        }
        // --- A tile: cvt staged regs -> bf16, linear ds_write_b128 ---
        #pragma unroll
        for (int j = 0; j < 4; j++) {
            union { s16x8 v; unsigned u[4]; } o;
            const f32x4 lo = ar[2 * j], hi = ar[2 * j + 1];
            o.u[0] = cvt_pk_bf16(lo.x, lo.y);
            o.u[1] = cvt_pk_bf16(lo.z, lo.w);
            o.u[2] = cvt_pk_bf16(hi.x, hi.y);
            o.u[3] = cvt_pk_bf16(hi.z, hi.w);
            *(s16x8*)&As[(j * 256 + tid) * 8] = o.v;
        }
        __syncthreads();

        // prefetch next A tile into regs: latency hides under the MFMA phase
        if (kt + BK < INF) {
            const int ktn = kt + BK;
            #pragma unroll
            for (int j = 0; j < 4; j++) {
                const float* ga = A + (size_t)(m0 + arow[j]) * INF + ktn + akc[j] * 8;
                ar[2 * j]     = *(const f32x4*)ga;
                ar[2 * j + 1] = *(const f32x4*)(ga + 4);
            }
        }

        // --- fragments + MFMA, four 16-k steps ---
        #pragma unroll
        for (int ks = 0; ks < 4; ks++) {
            const int kc = ks * 2 + fr_kh;       // 8-ushort unit within BK
            s16x8 af[2], bf[2];
            #pragma unroll
            for (int mi = 0; mi < 2; mi++) {
                const int r = wm + mi * 32 + fr_row;
                af[mi] = *(const s16x8*)&As[(r * 8 + (kc ^ (r & 7))) * 8];
            }
            #pragma unroll
            for (int ni = 0; ni < 2; ni++) {
                const int r = wn + ni * 32 + fr_row;
                bf[ni] = *(const s16x8*)&Bs[(r * 8 + (kc ^ (r & 7))) * 8];
            }
            #pragma unroll
            for (int mi = 0; mi < 2; mi++)
                #pragma unroll
                for (int ni = 0; ni < 2; ni++)
                    acc[mi][ni] = __builtin_amdgcn_mfma_f32_32x32x16_bf16(
                        af[mi], bf[ni], acc[mi][ni], 0, 0, 0);
        }
        __syncthreads();
    }

    // --- epilogue: C/D col=lane&31, row=(reg&3)+8*(reg>>2)+4*(lane>>5) ---
    const int ccol = lane & 31;
    const int rbase = (lane >> 5) * 4;
    #pragma unroll
    for (int ni = 0; ni < 2; ni++) {
        const int n = n0 + wn + ni * 32 + ccol;
        const float bv = bias[n];
        #pragma unroll
        for (int mi = 0; mi < 2; mi++) {
            const int mb = m0 + wm + mi * 32 + rbase;
            #pragma unroll
            for (int r = 0; r < 16; r++) {
                const int m = mb + (r & 3) + 8 * (r >> 2);
                C[(size_t)m * OUTF + n] = acc[mi][ni][r] + bv;
            }
        }
    }
}

// ---------------------------------------------------------------------------
extern "C" void kernel_launch(void* const* d_in, const int* in_sizes, int n_in,
                              void* d_out, int out_size, void* d_ws, size_t ws_size,
                              hipStream_t stream) {
    (void)in_sizes; (void)n_in; (void)out_size; (void)ws_size;
    const float* x     = (const float*)d_in[0];
    const float* theta = (const float*)d_in[1];
    const float* W0    = (const float*)d_in[2];
    const float* bias  = (const float*)d_in[3];
    const float* BB    = (const float*)d_in[4];
    const float* GG    = (const float*)d_in[5];
    const int*   Pi    = (const int*)d_in[6];      // int64 inputs arrive as int32
    float* out = (float*)d_out;

    char* ws = (char*)d_ws;
    float*  T    = (float*)ws;                       // LL f32 = 4194304 B
    ushort* WB   = (ushort*)(ws + 4194304);          // 1024*768 bf16 = 1572864 B
    float*  PART = (float*)(ws + 5767168);           // 1024 f32 partials

    k3_gather_fwht_lo<<<1024, 256, 0, stream>>>(Pi, GG, BB, theta, T, PART);
    k4_fwht_hi<<<256, 256, 0, stream>>>(T, PART, W0, WB);
    k7_gemm  <<<dim3(MROWS/BM, OUTF/BN), 256, 0, stream>>>(x, WB, bias, out);
}

// Round 2
// 170.864 us; speedup vs baseline: 1.0501x; 1.0501x over previous
//
#include <hip/hip_runtime.h>
#include <hip/hip_bf16.h>

// ---------------------------------------------------------------------------
// GlobalIntrinsicLinear: Fastfood update + GEMM
//   LL = 1<<20, DD = 1024*768, OUT=1024, IN=768, M = 8*2048 = 16384
// Inputs: x(8,2048,768) f32, theta(2048) f32, W_0(1024,768) f32, b(1024) f32,
//         BB(LL) f32, GG(LL) f32, Pi(LL) int32 (harness narrows int64)
// Output: (8,2048,1024) f32
//
// R9: k7 reverted to bf16-A global_load_lds (R8's f32 reg-staging cost +19us).
//     FWHT side rebuilt around shuffle-FWHT: stages on lane bits via
//     __shfl_xor (no barriers), wave bits via single LDS round-trips with the
//     4-partner 2-stage combine. Barriers: k3 20->3, k4 10->3. T stored in
//     [lo4][hi] float4-blocked layout so k4 reads 16KB contiguous per block.
//     r01 (the two 1024-FWHTs of BB*theta) hoisted to a one-block k0.
//     x->bf16 cast is a dedicated streaming kernel k1.
// ---------------------------------------------------------------------------

#define LL (1 << 20)
#define DD (1024 * 768)
#define OUTF 1024
#define INF 768
#define MROWS 16384

typedef __attribute__((ext_vector_type(8))) short s16x8;
typedef __attribute__((ext_vector_type(4))) float f32x4;
typedef __attribute__((ext_vector_type(16))) float f32x16;

__device__ __forceinline__ unsigned short f2bf(float f) {
    union { float f; unsigned u; } v; v.f = f;
    unsigned r = v.u + 0x7FFF + ((v.u >> 16) & 1);   // RNE
    return (unsigned short)(r >> 16);
}

// packed f32->bf16 RNE; no builtin on gfx950 (m240)
__device__ __forceinline__ unsigned cvt_pk_bf16(float lo, float hi) {
    unsigned r;
    asm("v_cvt_pk_bf16_f32 %0, %1, %2" : "=v"(r) : "v"(lo), "v"(hi));
    return r;
}

// ---------------------------------------------------------------------------
// K0: r01g[2048] = { FWHT1024(BB[0:1024]*theta[0:1024]),
//                    FWHT1024(BB[1024:2048]*theta[1024:2048]) }
// One block, 256 threads. Thread t: row r=t>>7, tt=t&127 owns els 8tt..8tt+7.
// Bits 0-2 in-reg, bits 3-8 = lane bits via shfl, bit 9 = tt bit 6 via LDS.
// ---------------------------------------------------------------------------
__global__ void k0_r01(const float* __restrict__ BB, const float* __restrict__ theta,
                       float* __restrict__ r01g) {
    __shared__ float sx[2048];
    const int t = threadIdx.x;
    const int r = t >> 7, tt = t & 127, lane = t & 63;
    float v[8];
    {
        const float4 a0 = *(const float4*)&BB[r * 1024 + tt * 8];
        const float4 a1 = *(const float4*)&BB[r * 1024 + tt * 8 + 4];
        const float4 b0 = *(const float4*)&theta[r * 1024 + tt * 8];
        const float4 b1 = *(const float4*)&theta[r * 1024 + tt * 8 + 4];
        v[0] = a0.x * b0.x; v[1] = a0.y * b0.y; v[2] = a0.z * b0.z; v[3] = a0.w * b0.w;
        v[4] = a1.x * b1.x; v[5] = a1.y * b1.y; v[6] = a1.z * b1.z; v[7] = a1.w * b1.w;
    }
    float a;
    // h=1: (0,1)(2,3)(4,5)(6,7)
    a = v[0]; v[0] = a + v[1]; v[1] = a - v[1];
    a = v[2]; v[2] = a + v[3]; v[3] = a - v[3];
    a = v[4]; v[4] = a + v[5]; v[5] = a - v[5];
    a = v[6]; v[6] = a + v[7]; v[7] = a - v[7];
    // h=2: (0,2)(1,3)(4,6)(5,7)
    a = v[0]; v[0] = a + v[2]; v[2] = a - v[2];
    a = v[1]; v[1] = a + v[3]; v[3] = a - v[3];
    a = v[4]; v[4] = a + v[6]; v[6] = a - v[6];
    a = v[5]; v[5] = a + v[7]; v[7] = a - v[7];
    // h=4: (0,4)(1,5)(2,6)(3,7)
    a = v[0]; v[0] = a + v[4]; v[4] = a - v[4];
    a = v[1]; v[1] = a + v[5]; v[5] = a - v[5];
    a = v[2]; v[2] = a + v[6]; v[6] = a - v[6];
    a = v[3]; v[3] = a + v[7]; v[7] = a - v[7];
    // bits 3..8 = lane bits
    #pragma unroll
    for (int j = 0; j < 6; j++) {
        const float sgn = ((lane >> j) & 1) ? -1.0f : 1.0f;
        #pragma unroll
        for (int c = 0; c < 8; c++) {
            float o = __shfl_xor(v[c], 1 << j, 64);
            v[c] = fmaf(sgn, v[c], o);
        }
    }
    // bit 9 = tt bit 6 (cross-wave within the row)
    #pragma unroll
    for (int c = 0; c < 8; c++) sx[r * 1024 + tt * 8 + c] = v[c];
    __syncthreads();
    {
        const int pt = r * 1024 + (tt ^ 64) * 8;
        const float sgn = (tt & 64) ? -1.0f : 1.0f;
        #pragma unroll
        for (int c = 0; c < 8; c++) v[c] = fmaf(sgn, v[c], sx[pt + c]);
    }
    #pragma unroll
    for (int c = 0; c < 8; c++) r01g[r * 1024 + tt * 8 + c] = v[c];
}

// ---------------------------------------------------------------------------
// K1: x f32 -> bf16 cast, pure streaming. 75 MB traffic.
// ---------------------------------------------------------------------------
__global__ void k1_cast(const float* __restrict__ X, ushort* __restrict__ XB) {
    const f32x4* X4 = (const f32x4*)X;
    s16x8* O = (s16x8*)XB;
    size_t i = (size_t)blockIdx.x * 256 + threadIdx.x;
    #pragma unroll
    for (int j = 0; j < 3; j++, i += 524288) {
        const f32x4 A = X4[2 * i];
        const f32x4 B = X4[2 * i + 1];
        union { s16x8 v; unsigned u[4]; } o;
        o.u[0] = cvt_pk_bf16(A.x, A.y);
        o.u[1] = cvt_pk_bf16(A.z, A.w);
        o.u[2] = cvt_pk_bf16(B.x, B.y);
        o.u[3] = cvt_pk_bf16(B.z, B.w);
        O[i] = o.v;
    }
}

// ---------------------------------------------------------------------------
// K3: gather (Pi,GG) + lo-FWHT-1024 per hi-row + GG^2 partials.
// 256 blocks x 1024 threads; block b handles hi-rows 4b..4b+3 (sub-block
// s_r = t>>8, 256 threads each, tt = t&255 owns lo = 4tt..4tt+3).
// FWHT bits: 0-1 in-reg, 2-7 = lane bits (shfl), 8-9 = tt bits 6-7 (one LDS
// round, 4-partner combine). Output T2 in [lo4][hi] float4-blocked layout,
// written coalesced via LDS transpose.
// ---------------------------------------------------------------------------
__global__ __launch_bounds__(1024)
void k3_gather_fwht_lo(const int* __restrict__ Pi, const float* __restrict__ GG,
                       const float* __restrict__ r01g, f32x4* __restrict__ T2,
                       float* __restrict__ partial) {
    __shared__ float r01s[2048];
    __shared__ f32x4 sA[1024];       // 16 KB
    __shared__ float sB[4 * 1028];   // 16.4 KB (pitch 1028 breaks conflicts)
    __shared__ float ws[16];
    const int t = threadIdx.x;
    const int s_r = t >> 8, tt = t & 255, lane = t & 63;
    const int row = blockIdx.x * 4 + s_r;

    r01s[t] = r01g[t];
    r01s[t + 1024] = r01g[t + 1024];
    const int4   pv = ((const int4*)Pi)[row * 256 + tt];
    const float4 gv = ((const float4*)GG)[row * 256 + tt];
    // GG^2 block partial
    float g2 = gv.x * gv.x + gv.y * gv.y + gv.z * gv.z + gv.w * gv.w;
    #pragma unroll
    for (int o = 32; o > 0; o >>= 1) g2 += __shfl_down(g2, o, 64);
    if (lane == 0) ws[t >> 6] = g2;
    __syncthreads();   // r01s ready (ws too)

    float v[4];
    {
        int p; float g;
        p = pv.x; g = gv.x;
        v[0] = (r01s[p & 1023] + (((p >> 10) & 1) ? -1.0f : 1.0f) * r01s[1024 + (p & 1023)]) * g;
        p = pv.y; g = gv.y;
        v[1] = (r01s[p & 1023] + (((p >> 10) & 1) ? -1.0f : 1.0f) * r01s[1024 + (p & 1023)]) * g;
        p = pv.z; g = gv.z;
        v[2] = (r01s[p & 1023] + (((p >> 10) & 1) ? -1.0f : 1.0f) * r01s[1024 + (p & 1023)]) * g;
        p = pv.w; g = gv.w;
        v[3] = (r01s[p & 1023] + (((p >> 10) & 1) ? -1.0f : 1.0f) * r01s[1024 + (p & 1023)]) * g;
    }
    // bits 0-1 in-reg
    float a;
    a = v[0]; v[0] = a + v[1]; v[1] = a - v[1];
    a = v[2]; v[2] = a + v[3]; v[3] = a - v[3];
    a = v[0]; v[0] = a + v[2]; v[2] = a - v[2];
    a = v[1]; v[1] = a + v[3]; v[3] = a - v[3];
    // bits 2-7 = lane bits
    #pragma unroll
    for (int j = 0; j < 6; j++) {
        const float sgn = ((lane >> j) & 1) ? -1.0f : 1.0f;
        #pragma unroll
        for (int c = 0; c < 4; c++) {
            float o = __shfl_xor(v[c], 1 << j, 64);
            v[c] = fmaf(sgn, v[c], o);
        }
    }
    // bits 8-9 = tt bits 6-7: one LDS round, 4-partner 2-stage combine
    {
        f32x4 vv; vv.x = v[0]; vv.y = v[1]; vv.z = v[2]; vv.w = v[3];
        sA[t] = vv;
    }
    __syncthreads();
    {
        const int b = t & ~192;
        const f32x4 q00 = sA[b];
        const f32x4 q10 = sA[b + 64];
        const f32x4 q01 = sA[b + 128];
        const f32x4 q11 = sA[b + 192];
        const float s8 = (tt & 64) ? -1.0f : 1.0f;
        const float s9 = (tt & 128) ? -1.0f : 1.0f;
        #pragma unroll
        for (int c = 0; c < 4; c++)
            v[c] = (q00[c] + s9 * q01[c]) + s8 * (q10[c] + s9 * q11[c]);
    }
    // thread 0: publish block partial
    if (t == 0) {
        float s = 0;
        #pragma unroll
        for (int i = 0; i < 16; i++) s += ws[i];
        partial[blockIdx.x] = s;
    }
    // transpose via sB, then coalesced T2 write
    {
        f32x4 vv; vv.x = v[0]; vv.y = v[1]; vv.z = v[2]; vv.w = v[3];
        *(f32x4*)&sB[s_r * 1028 + 4 * tt] = vv;
    }
    __syncthreads();
    {
        const int rl = t & 3;          // row_local
        const int lo4 = t >> 2;        // 0..255
        const f32x4 w = *(const f32x4*)&sB[rl * 1028 + lo4 * 4];
        T2[(size_t)lo4 * 1024 + blockIdx.x * 4 + rl] = w;
    }
}

// ---------------------------------------------------------------------------
// K4: hi-FWHT-1024 per lo-column + W_eff epilogue.
// 256 blocks x 1024 threads; block g owns lo = 4g..4g+3 (one float4/thread,
// hi = t). Reads T2[g*1024 + t]: 16 KB contiguous. FWHT bits 0-5 via shfl,
// bits 6-7 and 8-9 via two LDS rounds (4-partner combine). 3 barriers total.
// ---------------------------------------------------------------------------
__global__ __launch_bounds__(1024)
void k4_fwht_hi(const f32x4* __restrict__ T2, const float* __restrict__ partial,
                const float* __restrict__ W0, ushort* __restrict__ WB) {
    __shared__ f32x4 sx[1024];   // 16 KB
    __shared__ float rw[17];
    const int t = threadIdx.x;
    const int g = blockIdx.x;
    const int lane = t & 63;

    float pr = 0.0f;
    if (t < 256) pr = partial[t];
    #pragma unroll
    for (int o = 32; o > 0; o >>= 1) pr += __shfl_down(pr, o, 64);
    if (t < 256 && lane == 0) rw[t >> 6] = pr;

    f32x4 vv = T2[(size_t)g * 1024 + t];
    // bits 0-5 = lane bits
    #pragma unroll
    for (int j = 0; j < 6; j++) {
        const float sgn = ((lane >> j) & 1) ? -1.0f : 1.0f;
        #pragma unroll
        for (int c = 0; c < 4; c++) {
            float o = __shfl_xor(vv[c], 1 << j, 64);
            vv[c] = fmaf(sgn, vv[c], o);
        }
    }
    // round A: bits 6-7
    sx[t] = vv;
    __syncthreads();   // sx + rw[0..3] ready
    if (t == 0) rw[16] = rw[0] + rw[1] + rw[2] + rw[3];
    {
        const int b = t & ~192;
        const f32x4 q00 = sx[b];
        const f32x4 q10 = sx[b + 64];
        const f32x4 q01 = sx[b + 128];
        const f32x4 q11 = sx[b + 192];
        const float s6 = (t & 64) ? -1.0f : 1.0f;
        const float s7 = (t & 128) ? -1.0f : 1.0f;
        #pragma unroll
        for (int c = 0; c < 4; c++)
            vv[c] = (q00[c] + s7 * q01[c]) + s6 * (q10[c] + s7 * q11[c]);
    }
    __syncthreads();   // protect sx overwrite; publishes rw[16]
    // round B: bits 8-9
    sx[t] = vv;
    __syncthreads();
    {
        const int b = t & ~768;
        const f32x4 q00 = sx[b];
        const f32x4 q10 = sx[b + 256];
        const f32x4 q01 = sx[b + 512];
        const f32x4 q11 = sx[b + 768];
        const float s8 = (t & 256) ? -1.0f : 1.0f;
        const float s9 = (t & 512) ? -1.0f : 1.0f;
        #pragma unroll
        for (int c = 0; c < 4; c++)
            vv[c] = (q00[c] + s9 * q01[c]) + s8 * (q10[c] + s9 * q11[c]);
    }
    // epilogue: hi = t, lo = 4g..4g+3, p = hi*1024 + lo < DD <=> hi < 768
    if (t < 768) {
        const float scale = rsqrtf(rw[16] * (float)DD);
        const size_t d = (size_t)t * 1024 + 4 * g;
        const float4 w = *(const float4*)&W0[d];
        ushort4 o;
        o.x = f2bf(w.x + vv.x * scale);
        o.y = f2bf(w.y + vv.y * scale);
        o.z = f2bf(w.z + vv.z * scale);
        o.w = f2bf(w.w + vv.w * scale);
        *(ushort4*)&WB[d] = o;
    }
}

// ---------------------------------------------------------------------------
// K7: GEMM  C[m][n] = sum_k A[m][k]*B[n][k] + bias[n]   (R0-verified form)
// A: MROWS x 768 bf16, B: 1024 x 768 bf16 (W_eff), C: f32.
// 128x128 tile, BK=64, 4 waves (2x2), each wave 2x2 MFMA 32x32x16 tiles
// x4 k-steps. 16 ds_read_b128 + 16 MFMA per K-iter.
// XOR-swizzled LDS: 16B slot s <-> row = s>>3, kc = (s&7) ^ (row&7).
// C/D: col = lane&31, row = (reg&3) + 8*(reg>>2) + 4*(lane>>5)  [m74/m101].
// ---------------------------------------------------------------------------
#define BM 128
#define BN 128
#define BK 64

__global__ __launch_bounds__(256)
void k7_gemm(const ushort* __restrict__ A, const ushort* __restrict__ B,
             const float* __restrict__ bias, float* __restrict__ C) {
    __shared__ ushort As[BM * BK];   // 16 KB
    __shared__ ushort Bs[BN * BK];   // 16 KB
    const int tid  = threadIdx.x;
    const int lane = tid & 63;
    const int wave = tid >> 6;
    const int m0 = blockIdx.x * BM;
    const int n0 = blockIdx.y * BN;
    const int wm = (wave & 1) * 64;
    const int wn = (wave >> 1) * 64;

    const int fr_row = lane & 31;     // row within 32-tile
    const int fr_kh  = lane >> 5;     // k-half 0..1 (8 k each)

    f32x16 acc[2][2];
    #pragma unroll
    for (int i = 0; i < 2; i++)
        #pragma unroll
        for (int j = 0; j < 2; j++) acc[i][j] = (f32x16)(0.0f);

    for (int kt = 0; kt < INF; kt += BK) {
        // --- stage A/B tiles: 1024 slots x 16B each; XOR-swizzled mapping ---
        #pragma unroll
        for (int i = 0; i < 4; i++) {
            const int s   = i * 256 + tid;       // LDS slot (16B units)
            const int row = s >> 3;
            const int kc  = (s & 7) ^ (row & 7);
            const ushort* ga = A + (size_t)(m0 + row) * INF + kt + kc * 8;
            const ushort* gb = B + (size_t)(n0 + row) * INF + kt + kc * 8;
            __builtin_amdgcn_global_load_lds(
                (const __attribute__((address_space(1))) void*)ga,
                (__attribute__((address_space(3))) void*)&As[i * 2048 + wave * 512], 16, 0, 0);
            __builtin_amdgcn_global_load_lds(
                (const __attribute__((address_space(1))) void*)gb,
                (__attribute__((address_space(3))) void*)&Bs[i * 2048 + wave * 512], 16, 0, 0);
        }
        __syncthreads();

        // --- fragments + MFMA, four 16-k steps ---
        #pragma unroll
        for (int ks = 0; ks < 4; ks++) {
            const int kc = ks * 2 + fr_kh;       // 8-ushort unit within BK
            s16x8 af[2], bf[2];
            #pragma unroll
            for (int mi = 0; mi < 2; mi++) {
                const int r = wm + mi * 32 + fr_row;
                af[mi] = *(const s16x8*)&As[(r * 8 + (kc ^ (r & 7))) * 8];
            }
            #pragma unroll
            for (int ni = 0; ni < 2; ni++) {
                const int r = wn + ni * 32 + fr_row;
                bf[ni] = *(const s16x8*)&Bs[(r * 8 + (kc ^ (r & 7))) * 8];
            }
            #pragma unroll
            for (int mi = 0; mi < 2; mi++)
                #pragma unroll
                for (int ni = 0; ni < 2; ni++)
                    acc[mi][ni] = __builtin_amdgcn_mfma_f32_32x32x16_bf16(
                        af[mi], bf[ni], acc[mi][ni], 0, 0, 0);
        }
        __syncthreads();
    }

    // --- epilogue: C/D col=lane&31, row=(reg&3)+8*(reg>>2)+4*(lane>>5) ---
    const int ccol = lane & 31;
    const int rbase = (lane >> 5) * 4;
    #pragma unroll
    for (int ni = 0; ni < 2; ni++) {
        const int n = n0 + wn + ni * 32 + ccol;
        const float bv = bias[n];
        #pragma unroll
        for (int mi = 0; mi < 2; mi++) {
            const int mb = m0 + wm + mi * 32 + rbase;
            #pragma unroll
            for (int r = 0; r < 16; r++) {
                const int m = mb + (r & 3) + 8 * (r >> 2);
                C[(size_t)m * OUTF + n] = acc[mi][ni][r] + bv;
            }
        }
    }
}

// ---------------------------------------------------------------------------
extern "C" void kernel_launch(void* const* d_in, const int* in_sizes, int n_in,
                              void* d_out, int out_size, void* d_ws, size_t ws_size,
                              hipStream_t stream) {
    (void)in_sizes; (void)n_in; (void)out_size; (void)ws_size;
    const float* x     = (const float*)d_in[0];
    const float* theta = (const float*)d_in[1];
    const float* W0    = (const float*)d_in[2];
    const float* bias  = (const float*)d_in[3];
    const float* BB    = (const float*)d_in[4];
    const float* GG    = (const float*)d_in[5];
    const int*   Pi    = (const int*)d_in[6];      // int64 inputs arrive as int32
    float* out = (float*)d_out;

    char* ws = (char*)d_ws;
    ushort* XB   = (ushort*)ws;                      // 16384*768 bf16 = 25165824 B
    f32x4*  T2   = (f32x4*)(ws + 25165824);          // LL f32 = 4194304 B
    ushort* WB   = (ushort*)(ws + 29360128);         // 1024*768 bf16 = 1572864 B
    float*  R01  = (float*)(ws + 30932992);          // 2048 f32 = 8192 B
    float*  PART = (float*)(ws + 30941184);          // 256 f32 partials

    k0_r01          <<<1,    256, 0, stream>>>(BB, theta, R01);
    k1_cast         <<<2048, 256, 0, stream>>>(x, XB);
    k3_gather_fwht_lo<<<256, 1024, 0, stream>>>(Pi, GG, R01, T2, PART);
    k4_fwht_hi      <<<256, 1024, 0, stream>>>(T2, PART, W0, WB);
    k7_gemm<<<dim3(MROWS/BM, OUTF/BN), 256, 0, stream>>>(XB, WB, bias, out);
}

// Round 3
// 165.061 us; speedup vs baseline: 1.0870x; 1.0352x over previous
//
#include <hip/hip_runtime.h>
#include <hip/hip_bf16.h>

// ---------------------------------------------------------------------------
// GlobalIntrinsicLinear: Fastfood update + GEMM
//   LL = 1<<20, DD = 1024*768, OUT=1024, IN=768, M = 8*2048 = 16384
// Inputs: x(8,2048,768) f32, theta(2048) f32, W_0(1024,768) f32, b(1024) f32,
//         BB(LL) f32, GG(LL) f32, Pi(LL) int32 (harness narrows int64)
// Output: (8,2048,1024) f32
//
// R10: k7 -> 2-phase double-buffered pipeline (T3 minimum recipe): stage
//      tile t+1 BEFORE computing tile t, one barrier per K-iter (was 2).
//      Exposed global_load_lds latency (~600-900cy/iter, 12 iters) now hides
//      under the 64-MFMA compute phase. LDS 32->64 KB.
//      k0 fused into k1's grid as block 2048 (one fewer dispatch).
//      FWHT side (R9 shuffle-FWHT structure) unchanged.
// ---------------------------------------------------------------------------

#define LL (1 << 20)
#define DD (1024 * 768)
#define OUTF 1024
#define INF 768
#define MROWS 16384

typedef __attribute__((ext_vector_type(8))) short s16x8;
typedef __attribute__((ext_vector_type(4))) float f32x4;
typedef __attribute__((ext_vector_type(16))) float f32x16;

__device__ __forceinline__ unsigned short f2bf(float f) {
    union { float f; unsigned u; } v; v.f = f;
    unsigned r = v.u + 0x7FFF + ((v.u >> 16) & 1);   // RNE
    return (unsigned short)(r >> 16);
}

// packed f32->bf16 RNE; no builtin on gfx950 (m240)
__device__ __forceinline__ unsigned cvt_pk_bf16(float lo, float hi) {
    unsigned r;
    asm("v_cvt_pk_bf16_f32 %0, %1, %2" : "=v"(r) : "v"(lo), "v"(hi));
    return r;
}

// ---------------------------------------------------------------------------
// K01: fused {x f32 -> bf16 cast (blocks 0..2047)} + {r01 FWHT (block 2048)}.
// r01g[2048] = { FWHT1024(BB[0:1024]*theta[0:1024]),
//                FWHT1024(BB[1024:2048]*theta[1024:2048]) }
// r01 block: thread t: row r=t>>7, tt=t&127 owns els 8tt..8tt+7.
// Bits 0-2 in-reg, bits 3-8 = lane bits via shfl, bit 9 = tt bit 6 via LDS.
// ---------------------------------------------------------------------------
__global__ void k01_cast_r01(const float* __restrict__ X, ushort* __restrict__ XB,
                             const float* __restrict__ BB, const float* __restrict__ theta,
                             float* __restrict__ r01g) {
    __shared__ float sx[2048];
    const int t = threadIdx.x;
    if (blockIdx.x < 2048) {
        const f32x4* X4 = (const f32x4*)X;
        s16x8* O = (s16x8*)XB;
        size_t i = (size_t)blockIdx.x * 256 + t;
        #pragma unroll
        for (int j = 0; j < 3; j++, i += 524288) {
            const f32x4 A = X4[2 * i];
            const f32x4 B = X4[2 * i + 1];
            union { s16x8 v; unsigned u[4]; } o;
            o.u[0] = cvt_pk_bf16(A.x, A.y);
            o.u[1] = cvt_pk_bf16(A.z, A.w);
            o.u[2] = cvt_pk_bf16(B.x, B.y);
            o.u[3] = cvt_pk_bf16(B.z, B.w);
            O[i] = o.v;
        }
        return;
    }
    // ---- r01 block ----
    const int r = t >> 7, tt = t & 127, lane = t & 63;
    float v[8];
    {
        const float4 a0 = *(const float4*)&BB[r * 1024 + tt * 8];
        const float4 a1 = *(const float4*)&BB[r * 1024 + tt * 8 + 4];
        const float4 b0 = *(const float4*)&theta[r * 1024 + tt * 8];
        const float4 b1 = *(const float4*)&theta[r * 1024 + tt * 8 + 4];
        v[0] = a0.x * b0.x; v[1] = a0.y * b0.y; v[2] = a0.z * b0.z; v[3] = a0.w * b0.w;
        v[4] = a1.x * b1.x; v[5] = a1.y * b1.y; v[6] = a1.z * b1.z; v[7] = a1.w * b1.w;
    }
    float a;
    a = v[0]; v[0] = a + v[1]; v[1] = a - v[1];
    a = v[2]; v[2] = a + v[3]; v[3] = a - v[3];
    a = v[4]; v[4] = a + v[5]; v[5] = a - v[5];
    a = v[6]; v[6] = a + v[7]; v[7] = a - v[7];
    a = v[0]; v[0] = a + v[2]; v[2] = a - v[2];
    a = v[1]; v[1] = a + v[3]; v[3] = a - v[3];
    a = v[4]; v[4] = a + v[6]; v[6] = a - v[6];
    a = v[5]; v[5] = a + v[7]; v[7] = a - v[7];
    a = v[0]; v[0] = a + v[4]; v[4] = a - v[4];
    a = v[1]; v[1] = a + v[5]; v[5] = a - v[5];
    a = v[2]; v[2] = a + v[6]; v[6] = a - v[6];
    a = v[3]; v[3] = a + v[7]; v[7] = a - v[7];
    #pragma unroll
    for (int j = 0; j < 6; j++) {
        const float sgn = ((lane >> j) & 1) ? -1.0f : 1.0f;
        #pragma unroll
        for (int c = 0; c < 8; c++) {
            float o = __shfl_xor(v[c], 1 << j, 64);
            v[c] = fmaf(sgn, v[c], o);
        }
    }
    #pragma unroll
    for (int c = 0; c < 8; c++) sx[r * 1024 + tt * 8 + c] = v[c];
    __syncthreads();
    {
        const int pt = r * 1024 + (tt ^ 64) * 8;
        const float sgn = (tt & 64) ? -1.0f : 1.0f;
        #pragma unroll
        for (int c = 0; c < 8; c++) v[c] = fmaf(sgn, v[c], sx[pt + c]);
    }
    #pragma unroll
    for (int c = 0; c < 8; c++) r01g[r * 1024 + tt * 8 + c] = v[c];
}

// ---------------------------------------------------------------------------
// K3: gather (Pi,GG) + lo-FWHT-1024 per hi-row + GG^2 partials.
// 256 blocks x 1024 threads; block b handles hi-rows 4b..4b+3 (sub-block
// s_r = t>>8, 256 threads each, tt = t&255 owns lo = 4tt..4tt+3).
// FWHT bits: 0-1 in-reg, 2-7 = lane bits (shfl), 8-9 = tt bits 6-7 (one LDS
// round, 4-partner combine). Output T2 in [lo4][hi] float4-blocked layout,
// written coalesced via LDS transpose.
// ---------------------------------------------------------------------------
__global__ __launch_bounds__(1024)
void k3_gather_fwht_lo(const int* __restrict__ Pi, const float* __restrict__ GG,
                       const float* __restrict__ r01g, f32x4* __restrict__ T2,
                       float* __restrict__ partial) {
    __shared__ float r01s[2048];
    __shared__ f32x4 sA[1024];       // 16 KB
    __shared__ float sB[4 * 1028];   // 16.4 KB (pitch 1028 breaks conflicts)
    __shared__ float ws[16];
    const int t = threadIdx.x;
    const int s_r = t >> 8, tt = t & 255, lane = t & 63;
    const int row = blockIdx.x * 4 + s_r;

    r01s[t] = r01g[t];
    r01s[t + 1024] = r01g[t + 1024];
    const int4   pv = ((const int4*)Pi)[row * 256 + tt];
    const float4 gv = ((const float4*)GG)[row * 256 + tt];
    float g2 = gv.x * gv.x + gv.y * gv.y + gv.z * gv.z + gv.w * gv.w;
    #pragma unroll
    for (int o = 32; o > 0; o >>= 1) g2 += __shfl_down(g2, o, 64);
    if (lane == 0) ws[t >> 6] = g2;
    __syncthreads();   // r01s ready (ws too)

    float v[4];
    {
        int p; float g;
        p = pv.x; g = gv.x;
        v[0] = (r01s[p & 1023] + (((p >> 10) & 1) ? -1.0f : 1.0f) * r01s[1024 + (p & 1023)]) * g;
        p = pv.y; g = gv.y;
        v[1] = (r01s[p & 1023] + (((p >> 10) & 1) ? -1.0f : 1.0f) * r01s[1024 + (p & 1023)]) * g;
        p = pv.z; g = gv.z;
        v[2] = (r01s[p & 1023] + (((p >> 10) & 1) ? -1.0f : 1.0f) * r01s[1024 + (p & 1023)]) * g;
        p = pv.w; g = gv.w;
        v[3] = (r01s[p & 1023] + (((p >> 10) & 1) ? -1.0f : 1.0f) * r01s[1024 + (p & 1023)]) * g;
    }
    float a;
    a = v[0]; v[0] = a + v[1]; v[1] = a - v[1];
    a = v[2]; v[2] = a + v[3]; v[3] = a - v[3];
    a = v[0]; v[0] = a + v[2]; v[2] = a - v[2];
    a = v[1]; v[1] = a + v[3]; v[3] = a - v[3];
    #pragma unroll
    for (int j = 0; j < 6; j++) {
        const float sgn = ((lane >> j) & 1) ? -1.0f : 1.0f;
        #pragma unroll
        for (int c = 0; c < 4; c++) {
            float o = __shfl_xor(v[c], 1 << j, 64);
            v[c] = fmaf(sgn, v[c], o);
        }
    }
    {
        f32x4 vv; vv.x = v[0]; vv.y = v[1]; vv.z = v[2]; vv.w = v[3];
        sA[t] = vv;
    }
    __syncthreads();
    {
        const int b = t & ~192;
        const f32x4 q00 = sA[b];
        const f32x4 q10 = sA[b + 64];
        const f32x4 q01 = sA[b + 128];
        const f32x4 q11 = sA[b + 192];
        const float s8 = (tt & 64) ? -1.0f : 1.0f;
        const float s9 = (tt & 128) ? -1.0f : 1.0f;
        #pragma unroll
        for (int c = 0; c < 4; c++)
            v[c] = (q00[c] + s9 * q01[c]) + s8 * (q10[c] + s9 * q11[c]);
    }
    if (t == 0) {
        float s = 0;
        #pragma unroll
        for (int i = 0; i < 16; i++) s += ws[i];
        partial[blockIdx.x] = s;
    }
    {
        f32x4 vv; vv.x = v[0]; vv.y = v[1]; vv.z = v[2]; vv.w = v[3];
        *(f32x4*)&sB[s_r * 1028 + 4 * tt] = vv;
    }
    __syncthreads();
    {
        const int rl = t & 3;          // row_local
        const int lo4 = t >> 2;        // 0..255
        const f32x4 w = *(const f32x4*)&sB[rl * 1028 + lo4 * 4];
        T2[(size_t)lo4 * 1024 + blockIdx.x * 4 + rl] = w;
    }
}

// ---------------------------------------------------------------------------
// K4: hi-FWHT-1024 per lo-column + W_eff epilogue.
// 256 blocks x 1024 threads; block g owns lo = 4g..4g+3 (one float4/thread,
// hi = t). Reads T2[g*1024 + t]: 16 KB contiguous. FWHT bits 0-5 via shfl,
// bits 6-7 and 8-9 via two LDS rounds (4-partner combine). 3 barriers total.
// ---------------------------------------------------------------------------
__global__ __launch_bounds__(1024)
void k4_fwht_hi(const f32x4* __restrict__ T2, const float* __restrict__ partial,
                const float* __restrict__ W0, ushort* __restrict__ WB) {
    __shared__ f32x4 sx[1024];   // 16 KB
    __shared__ float rw[17];
    const int t = threadIdx.x;
    const int g = blockIdx.x;
    const int lane = t & 63;

    float pr = 0.0f;
    if (t < 256) pr = partial[t];
    #pragma unroll
    for (int o = 32; o > 0; o >>= 1) pr += __shfl_down(pr, o, 64);
    if (t < 256 && lane == 0) rw[t >> 6] = pr;

    f32x4 vv = T2[(size_t)g * 1024 + t];
    #pragma unroll
    for (int j = 0; j < 6; j++) {
        const float sgn = ((lane >> j) & 1) ? -1.0f : 1.0f;
        #pragma unroll
        for (int c = 0; c < 4; c++) {
            float o = __shfl_xor(vv[c], 1 << j, 64);
            vv[c] = fmaf(sgn, vv[c], o);
        }
    }
    sx[t] = vv;
    __syncthreads();   // sx + rw[0..3] ready
    if (t == 0) rw[16] = rw[0] + rw[1] + rw[2] + rw[3];
    {
        const int b = t & ~192;
        const f32x4 q00 = sx[b];
        const f32x4 q10 = sx[b + 64];
        const f32x4 q01 = sx[b + 128];
        const f32x4 q11 = sx[b + 192];
        const float s6 = (t & 64) ? -1.0f : 1.0f;
        const float s7 = (t & 128) ? -1.0f : 1.0f;
        #pragma unroll
        for (int c = 0; c < 4; c++)
            vv[c] = (q00[c] + s7 * q01[c]) + s6 * (q10[c] + s7 * q11[c]);
    }
    __syncthreads();   // protect sx overwrite; publishes rw[16]
    sx[t] = vv;
    __syncthreads();
    {
        const int b = t & ~768;
        const f32x4 q00 = sx[b];
        const f32x4 q10 = sx[b + 256];
        const f32x4 q01 = sx[b + 512];
        const f32x4 q11 = sx[b + 768];
        const float s8 = (t & 256) ? -1.0f : 1.0f;
        const float s9 = (t & 512) ? -1.0f : 1.0f;
        #pragma unroll
        for (int c = 0; c < 4; c++)
            vv[c] = (q00[c] + s9 * q01[c]) + s8 * (q10[c] + s9 * q11[c]);
    }
    if (t < 768) {
        const float scale = rsqrtf(rw[16] * (float)DD);
        const size_t d = (size_t)t * 1024 + 4 * g;
        const float4 w = *(const float4*)&W0[d];
        ushort4 o;
        o.x = f2bf(w.x + vv.x * scale);
        o.y = f2bf(w.y + vv.y * scale);
        o.z = f2bf(w.z + vv.z * scale);
        o.w = f2bf(w.w + vv.w * scale);
        *(ushort4*)&WB[d] = o;
    }
}

// ---------------------------------------------------------------------------
// K7: GEMM  C[m][n] = sum_k A[m][k]*B[n][k] + bias[n]
// A: MROWS x 768 bf16, B: 1024 x 768 bf16 (W_eff), C: f32.
// 128x128 tile, BK=64, 4 waves (2x2), each wave 2x2 MFMA 32x32x16 tiles
// x4 k-steps. R10: double-buffered LDS + stage-before-compute (T3 minimum):
//   prologue: STAGE(buf0, t=0); barrier
//   iter t:   STAGE(buf[t+1 & 1], t+1); ds_read+MFMA on buf[t&1]; barrier
// One barrier per K-iter (auto vmcnt/lgkm drain covers both hazards).
// XOR-swizzled LDS: 16B slot s <-> row = s>>3, kc = (s&7) ^ (row&7).
// C/D: col = lane&31, row = (reg&3) + 8*(reg>>2) + 4*(lane>>5)  [m74/m101].
// ---------------------------------------------------------------------------
#define BM 128
#define BN 128
#define BK 64
#define KITERS (INF / BK)   // 12

__global__ __launch_bounds__(256)
void k7_gemm(const ushort* __restrict__ A, const ushort* __restrict__ B,
             const float* __restrict__ bias, float* __restrict__ C) {
    __shared__ ushort As[2][BM * BK];   // 2 x 16 KB
    __shared__ ushort Bs[2][BN * BK];   // 2 x 16 KB
    const int tid  = threadIdx.x;
    const int lane = tid & 63;
    const int wave = tid >> 6;
    const int m0 = blockIdx.x * BM;
    const int n0 = blockIdx.y * BN;
    const int wm = (wave & 1) * 64;
    const int wn = (wave >> 1) * 64;

    const int fr_row = lane & 31;     // row within 32-tile
    const int fr_kh  = lane >> 5;     // k-half 0..1 (8 k each)

    f32x16 acc[2][2];
    #pragma unroll
    for (int i = 0; i < 2; i++)
        #pragma unroll
        for (int j = 0; j < 2; j++) acc[i][j] = (f32x16)(0.0f);

    // stage k-tile kt into buffer bsel (8 global_load_lds, 16B each)
    auto stage = [&](int bsel, int kt) {
        #pragma unroll
        for (int i = 0; i < 4; i++) {
            const int s   = i * 256 + tid;       // LDS slot (16B units)
            const int row = s >> 3;
            const int kc  = (s & 7) ^ (row & 7);
            const ushort* ga = A + (size_t)(m0 + row) * INF + kt + kc * 8;
            const ushort* gb = B + (size_t)(n0 + row) * INF + kt + kc * 8;
            __builtin_amdgcn_global_load_lds(
                (const __attribute__((address_space(1))) void*)ga,
                (__attribute__((address_space(3))) void*)&As[bsel][i * 2048 + wave * 512], 16, 0, 0);
            __builtin_amdgcn_global_load_lds(
                (const __attribute__((address_space(1))) void*)gb,
                (__attribute__((address_space(3))) void*)&Bs[bsel][i * 2048 + wave * 512], 16, 0, 0);
        }
    };

    stage(0, 0);
    __syncthreads();                     // drains vmcnt(0): tile 0 ready

    for (int t = 0; t < KITERS; t++) {
        const int cur = t & 1;
        if (t + 1 < KITERS) stage(cur ^ 1, (t + 1) * BK);   // prefetch next tile

        // --- fragments + MFMA, four 16-k steps, from buf[cur] ---
        const ushort* Ab = As[cur];
        const ushort* Bb = Bs[cur];
        #pragma unroll
        for (int ks = 0; ks < 4; ks++) {
            const int kc = ks * 2 + fr_kh;       // 8-ushort unit within BK
            s16x8 af[2], bf[2];
            #pragma unroll
            for (int mi = 0; mi < 2; mi++) {
                const int r = wm + mi * 32 + fr_row;
                af[mi] = *(const s16x8*)&Ab[(r * 8 + (kc ^ (r & 7))) * 8];
            }
            #pragma unroll
            for (int ni = 0; ni < 2; ni++) {
                const int r = wn + ni * 32 + fr_row;
                bf[ni] = *(const s16x8*)&Bb[(r * 8 + (kc ^ (r & 7))) * 8];
            }
            #pragma unroll
            for (int mi = 0; mi < 2; mi++)
                #pragma unroll
                for (int ni = 0; ni < 2; ni++)
                    acc[mi][ni] = __builtin_amdgcn_mfma_f32_32x32x16_bf16(
                        af[mi], bf[ni], acc[mi][ni], 0, 0, 0);
        }
        // barrier: (a) all waves done reading buf[cur] -> next iter may
        // overwrite it; (b) auto vmcnt(0) drain -> prefetched tile ready.
        __syncthreads();
    }

    // --- epilogue: C/D col=lane&31, row=(reg&3)+8*(reg>>2)+4*(lane>>5) ---
    const int ccol = lane & 31;
    const int rbase = (lane >> 5) * 4;
    #pragma unroll
    for (int ni = 0; ni < 2; ni++) {
        const int n = n0 + wn + ni * 32 + ccol;
        const float bv = bias[n];
        #pragma unroll
        for (int mi = 0; mi < 2; mi++) {
            const int mb = m0 + wm + mi * 32 + rbase;
            #pragma unroll
            for (int r = 0; r < 16; r++) {
                const int m = mb + (r & 3) + 8 * (r >> 2);
                C[(size_t)m * OUTF + n] = acc[mi][ni][r] + bv;
            }
        }
    }
}

// ---------------------------------------------------------------------------
extern "C" void kernel_launch(void* const* d_in, const int* in_sizes, int n_in,
                              void* d_out, int out_size, void* d_ws, size_t ws_size,
                              hipStream_t stream) {
    (void)in_sizes; (void)n_in; (void)out_size; (void)ws_size;
    const float* x     = (const float*)d_in[0];
    const float* theta = (const float*)d_in[1];
    const float* W0    = (const float*)d_in[2];
    const float* bias  = (const float*)d_in[3];
    const float* BB    = (const float*)d_in[4];
    const float* GG    = (const float*)d_in[5];
    const int*   Pi    = (const int*)d_in[6];      // int64 inputs arrive as int32
    float* out = (float*)d_out;

    char* ws = (char*)d_ws;
    ushort* XB   = (ushort*)ws;                      // 16384*768 bf16 = 25165824 B
    f32x4*  T2   = (f32x4*)(ws + 25165824);          // LL f32 = 4194304 B
    ushort* WB   = (ushort*)(ws + 29360128);         // 1024*768 bf16 = 1572864 B
    float*  R01  = (float*)(ws + 30932992);          // 2048 f32 = 8192 B
    float*  PART = (float*)(ws + 30941184);          // 256 f32 partials

    k01_cast_r01    <<<2049, 256, 0, stream>>>(x, XB, BB, theta, R01);
    k3_gather_fwht_lo<<<256, 1024, 0, stream>>>(Pi, GG, R01, T2, PART);
    k4_fwht_hi      <<<256, 1024, 0, stream>>>(T2, PART, W0, WB);
    k7_gemm<<<dim3(MROWS/BM, OUTF/BN), 256, 0, stream>>>(XB, WB, bias, out);
}